// Round 12
// baseline (101.944 us; speedup 1.0000x reference)
//
#include <hip/hip_runtime.h>

// LogNorm moment-matching, v12 = v11 INSTRUMENTATION BUILD (REPS=5).
// Purpose: v2-v11 never appeared in the rocprof top-5 (harness fill ops
// at ~39us dominate). Looping the body 5x pushes main to ~60us so we
// finally read MfmaUtil / VALUBusy / Occupancy / FETCH / bank conflicts
// for the real workload. Output identical each rep (deterministic).
// Race-safety of the rep loop: all LDS reads (x1pT/x2pT/x2tp: between
// barrier1 and barrier2; accs/ssum_s: after barrier2) are fenced from
// the next rep's writes by the barrier pair — a wave can only pass
// rep N+1's barrier1 after ALL waves finished rep N's epilogue.
//
// Math and layout identical to v11 (passed, 15.34us):
//   e = exp(Z_mu + sigma^2/2); x1' = e/4; x2' = e*sigma/4
//   var_num'[s,g] = sum_{d<=c} sc*(w_sc w_sd corr_cd)*(x2'_c x2'_d)
//   Ssum' = W @ x1'; var = vn'/ss'^2; mu = log(ss')+log4-var/2

#define S_STATES 16
#define C_TYPES  64
#define G_GENES  20000
#define OUT_HALF (S_STATES * G_GENES)
#define NPAIR    96
#define PER_WAVE 24
#define REPS     5

typedef _Float16 f16x2 __attribute__((ext_vector_type(2)));
typedef _Float16 f16x8 __attribute__((ext_vector_type(8)));
typedef float    f32x4 __attribute__((ext_vector_type(4)));

union Frag8 { f16x2 p[4]; f16x8 v; uint4 u; _Float16 h[8]; };

// ---- Kernel P: frag-ordered f16 A panels (1 KB each; 98 KB total) ----
__global__ __launch_bounds__(64)
void build_A(const float* __restrict__ corr, const float* __restrict__ w,
             unsigned short* __restrict__ cwA)
{
    const int p    = blockIdx.x;          // 0..97
    const int lane = threadIdx.x;
    const int gl   = lane & 15;           // state (A row)
    const int q    = lane >> 4;
    Frag8 v;
    if (p < NPAIR) {
        const int dh = (p >= 64);
        const int c  = dh ? p - 32 : p;
        const int d0 = dh * 32 + q * 8;
        const float wc = w[gl * C_TYPES + c];
        const float4 c0 = *(const float4*)(corr + c * C_TYPES + d0);
        const float4 c1 = *(const float4*)(corr + c * C_TYPES + d0 + 4);
        const float4 w0 = *(const float4*)(w + gl * C_TYPES + d0);
        const float4 w1 = *(const float4*)(w + gl * C_TYPES + d0 + 4);
        const float cv[8] = {c0.x,c0.y,c0.z,c0.w,c1.x,c1.y,c1.z,c1.w};
        const float wv[8] = {w0.x,w0.y,w0.z,w0.w,w1.x,w1.y,w1.z,w1.w};
#pragma unroll
        for (int j = 0; j < 8; ++j) {
            const int d = d0 + j;
            const float sc = (d < c) ? 2.0f : (d == c ? 1.0f : 0.0f);
            v.h[j] = (_Float16)(sc * cv[j] * wc * wv[j]);
        }
    } else {
        const int k0 = (p - NPAIR) * 32 + q * 8;
        const float4 w0 = *(const float4*)(w + gl * C_TYPES + k0);
        const float4 w1 = *(const float4*)(w + gl * C_TYPES + k0 + 4);
        const float wv[8] = {w0.x,w0.y,w0.z,w0.w,w1.x,w1.y,w1.z,w1.w};
#pragma unroll
        for (int j = 0; j < 8; ++j) v.h[j] = (_Float16)wv[j];
    }
    *(uint4*)(cwA + (p << 9) + lane * 8) = v.u;
}

// ---- Kernel M: main (v11 body x REPS) ----
__global__ __launch_bounds__(256, 4)
void lognorm_main(const float* __restrict__ Z_mu,
                  const float* __restrict__ Z_sigma,
                  const unsigned short* __restrict__ cwA,
                  float* __restrict__ out)
{
    __shared__ f16x2 x2pT[32][35];
    __shared__ f16x2 x1pT[32][35];
    __shared__ f16x2 x2tp[C_TYPES][21];
    __shared__ float accs[4][S_STATES][33];
    __shared__ float ssum_s[S_STATES][33];

    const int gt    = blockIdx.x;        // 0..624, 32 genes (exact)
    const int tid   = threadIdx.x;
    const int w     = tid >> 6;
    const int lane  = tid & 63;
    const int gl    = lane & 15;
    const int q     = lane >> 4;
    const int gbase = gt * 32;

#pragma unroll 1
    for (int rep = 0; rep < REPS; ++rep) {

    // ---- X-phase ----
    {
        const int dp = tid >> 3;
        const int gq = tid & 7;
        const int ga = gq * 2;
        const float* zm0 = Z_mu    + (2*dp) * G_GENES + gbase + ga;
        const float* zs0 = Z_sigma + (2*dp) * G_GENES + gbase + ga;
        const float2 m00 = *(const float2*)zm0;
        const float2 m01 = *(const float2*)(zm0 + 16);
        const float2 m10 = *(const float2*)(zm0 + G_GENES);
        const float2 m11 = *(const float2*)(zm0 + G_GENES + 16);
        const float2 s00 = *(const float2*)zs0;
        const float2 s01 = *(const float2*)(zs0 + 16);
        const float2 s10 = *(const float2*)(zs0 + G_GENES);
        const float2 s11 = *(const float2*)(zs0 + G_GENES + 16);
        float x1v[2][2][2], x2v[2][2][2];
#define XDO(r,h,j,M,S) { const float s_=(S); const float e_=__expf(fmaf(0.5f*s_,s_,(M)))*0.25f; \
                         x1v[r][h][j]=e_; x2v[r][h][j]=e_*s_; }
        XDO(0,0,0, m00.x, s00.x) XDO(0,0,1, m00.y, s00.y)
        XDO(0,1,0, m01.x, s01.x) XDO(0,1,1, m01.y, s01.y)
        XDO(1,0,0, m10.x, s10.x) XDO(1,0,1, m10.y, s10.y)
        XDO(1,1,0, m11.x, s11.x) XDO(1,1,1, m11.y, s11.y)
#undef XDO
#pragma unroll
        for (int h = 0; h < 2; ++h)
#pragma unroll
            for (int j = 0; j < 2; ++j) {
                const int g = ga + j + 16 * h;
                f16x2 a, b;
                a.x = (_Float16)x2v[0][h][j]; a.y = (_Float16)x2v[1][h][j];
                b.x = (_Float16)x1v[0][h][j]; b.y = (_Float16)x1v[1][h][j];
                x2pT[g][dp] = a;
                x1pT[g][dp] = b;
            }
#pragma unroll
        for (int r = 0; r < 2; ++r)
#pragma unroll
            for (int j = 0; j < 2; ++j) {
                f16x2 a;
                a.x = (_Float16)x2v[r][0][j];
                a.y = (_Float16)x2v[r][1][j];
                x2tp[2*dp + r][ga + j] = a;
            }
    }
    __syncthreads();

    // ---- B sources ----
    f16x2 xh[2][4][2];
#pragma unroll
    for (int dh = 0; dh < 2; ++dh)
#pragma unroll
        for (int t = 0; t < 2; ++t)
#pragma unroll
            for (int jp = 0; jp < 4; ++jp)
                xh[dh][jp][t] = x2pT[gl + 16*t][dh*16 + q*4 + jp];

    f16x2 xct[PER_WAVE];
#pragma unroll
    for (int i = 0; i < PER_WAVE; ++i) {
        const int c = i*4 + w - ((i >= 16) ? 32 : 0);
        xct[i] = x2tp[c][gl];
    }

    // ---- K-loop ----
    const unsigned short* Abase = cwA + (w << 9) + lane * 8;
    f32x4 acc0a = {0.f,0.f,0.f,0.f}, acc0b = {0.f,0.f,0.f,0.f};
    f32x4 acc1a = {0.f,0.f,0.f,0.f}, acc1b = {0.f,0.f,0.f,0.f};
#pragma unroll
    for (int i = 0; i < PER_WAVE; ++i) {
        Frag8 af; af.u = *(const uint4*)(Abase + (i << 11));
        const int dh = (i >= 16) ? 1 : 0;
        Frag8 b0, b1;
#pragma unroll
        for (int jp = 0; jp < 4; ++jp) {
            f16x2 s0; s0.x = xct[i].x; s0.y = xct[i].x;
            f16x2 s1; s1.x = xct[i].y; s1.y = xct[i].y;
            b0.p[jp] = s0 * xh[dh][jp][0];
            b1.p[jp] = s1 * xh[dh][jp][1];
        }
        if (i & 1) {
            acc0b = __builtin_amdgcn_mfma_f32_16x16x32_f16(af.v, b0.v, acc0b, 0, 0, 0);
            acc1b = __builtin_amdgcn_mfma_f32_16x16x32_f16(af.v, b1.v, acc1b, 0, 0, 0);
        } else {
            acc0a = __builtin_amdgcn_mfma_f32_16x16x32_f16(af.v, b0.v, acc0a, 0, 0, 0);
            acc1a = __builtin_amdgcn_mfma_f32_16x16x32_f16(af.v, b1.v, acc1a, 0, 0, 0);
        }
    }
    const f32x4 acc0 = acc0a + acc0b;
    const f32x4 acc1 = acc1a + acc1b;
#pragma unroll
    for (int r = 0; r < 4; ++r) {
        accs[w][q*4 + r][gl]      = acc0[r];
        accs[w][q*4 + r][gl + 16] = acc1[r];
    }

    // ---- Ssum GEMM ----
    if (w < 2) {
        Frag8 wf0, wf1;
        wf0.u = *(const uint4*)(cwA + ((NPAIR + 0) << 9) + lane * 8);
        wf1.u = *(const uint4*)(cwA + ((NPAIR + 1) << 9) + lane * 8);
        Frag8 x1f[2];
#pragma unroll
        for (int kk = 0; kk < 2; ++kk)
#pragma unroll
            for (int jp = 0; jp < 4; ++jp)
                x1f[kk].p[jp] = x1pT[gl + 16*w][kk*16 + q*4 + jp];
        f32x4 sa = {0.f,0.f,0.f,0.f};
        sa = __builtin_amdgcn_mfma_f32_16x16x32_f16(wf0.v, x1f[0].v, sa, 0, 0, 0);
        sa = __builtin_amdgcn_mfma_f32_16x16x32_f16(wf1.v, x1f[1].v, sa, 0, 0, 0);
#pragma unroll
        for (int r = 0; r < 4; ++r) ssum_s[q*4 + r][gl + 16*w] = sa[r];
    }
    __syncthreads();

    // ---- epilogue ----
    {
        const int s  = tid >> 4;
        const int gx = tid & 15;
#pragma unroll
        for (int t = 0; t < 2; ++t) {
            const int gg = gx + 16 * t;
            const float vn = (accs[0][s][gg] + accs[1][s][gg])
                           + (accs[2][s][gg] + accs[3][s][gg]);
            const float ss   = ssum_s[s][gg];
            const float rvar = fmaxf(vn, 0.f) / (ss * ss);
            out[s * G_GENES + gbase + gg] =
                __logf(ss) + 1.3862943611f - 0.5f * rvar;
            out[OUT_HALF + s * G_GENES + gbase + gg] = sqrtf(rvar);
        }
    }

    }  // rep loop
}

extern "C" void kernel_launch(void* const* d_in, const int* in_sizes, int n_in,
                              void* d_out, int out_size, void* d_ws, size_t ws_size,
                              hipStream_t stream) {
    const float* Z_mu      = (const float*)d_in[0];
    const float* Z_sigma   = (const float*)d_in[1];
    const float* corr      = (const float*)d_in[2];
    const float* cell_prob = (const float*)d_in[3];
    float* out = (float*)d_out;
    unsigned short* cwA = (unsigned short*)d_ws;

    build_A<<<dim3(NPAIR + 2), dim3(64), 0, stream>>>(corr, cell_prob, cwA);

    const int gtiles = G_GENES / 32;               // 625, exact
    lognorm_main<<<dim3(gtiles), dim3(256), 0, stream>>>(
        Z_mu, Z_sigma, cwA, out);
}

// Round 13
// 17.930 us; speedup vs baseline: 5.6858x; 5.6858x over previous
//
#include <hip/hip_runtime.h>

// LogNorm moment-matching, v13: 64-gene blocks (16 waves) — halve A-traffic,
// double active occupancy. Driven by R12 counters: MfmaUtil 4%, VALUBusy 8%,
// Occ 22%, TCC traffic ~23 KB/wave/rep == the cwA A-panel stream.
//
//   e = exp(Z_mu + sigma^2/2); x1' = e/4; x2' = e*sigma/4        (C x G)
//   var_num'[s,g] = sum_{d<=c} sc * (w_sc w_sd corr_cd) * (x2'_c x2'_d)
//   Ssum'[s,g]    = W @ x1'; var = vn'/ss'^2 (scales cancel);
//   mu = log(ss') + log4 - var/2 ; sigma = sqrt(var)
//
// Geometry: 313 blocks x 1024 thr (16 waves); block covers 64 genes
// (4 MFMA gene-subtiles), all 96 triangular panels once: wave w takes
// p = i*16 + w, i in [0,6), dh = (i>=4) compile-time. A-bytes/gene halved
// vs v11 (96 KB per 64 genes). LDS ~96 KB -> 1 block/CU (16 waves actives).
// Tail: block 312 windows to genes 19936..19999; overlap with block 311
// recomputes identical values (benign duplicate writes).
//
// MFMA 16x16x32_f16, layout as verified v2-v12:
//   A-frag: lane(q,gl) = A[m=gl][k=q*8+j]   (m = state)
//   B-frag: lane(q,gl) = B[k=q*8+j][n=gl]   (n = gene)
//   C/D:    lane(q,gl) reg r = D[row=q*4+r][col=gl]

#define S_STATES 16
#define C_TYPES  64
#define G_GENES  20000
#define OUT_HALF (S_STATES * G_GENES)
#define NPAIR    96

typedef _Float16 f16x2 __attribute__((ext_vector_type(2)));
typedef _Float16 f16x8 __attribute__((ext_vector_type(8)));
typedef float    f32x4 __attribute__((ext_vector_type(4)));

union Frag8 { f16x2 p[4]; f16x8 v; uint4 u; _Float16 h[8]; };

// ---- Kernel P: frag-ordered f16 A panels (1 KB each; 98 KB total) ----
__global__ __launch_bounds__(64)
void build_A(const float* __restrict__ corr, const float* __restrict__ w,
             unsigned short* __restrict__ cwA)
{
    const int p    = blockIdx.x;          // 0..97
    const int lane = threadIdx.x;
    const int gl   = lane & 15;           // state (A row)
    const int q    = lane >> 4;
    Frag8 v;
    if (p < NPAIR) {
        const int dh = (p >= 64);
        const int c  = dh ? p - 32 : p;
        const int d0 = dh * 32 + q * 8;
        const float wc = w[gl * C_TYPES + c];
        const float4 c0 = *(const float4*)(corr + c * C_TYPES + d0);
        const float4 c1 = *(const float4*)(corr + c * C_TYPES + d0 + 4);
        const float4 w0 = *(const float4*)(w + gl * C_TYPES + d0);
        const float4 w1 = *(const float4*)(w + gl * C_TYPES + d0 + 4);
        const float cv[8] = {c0.x,c0.y,c0.z,c0.w,c1.x,c1.y,c1.z,c1.w};
        const float wv[8] = {w0.x,w0.y,w0.z,w0.w,w1.x,w1.y,w1.z,w1.w};
#pragma unroll
        for (int j = 0; j < 8; ++j) {
            const int d = d0 + j;
            const float sc = (d < c) ? 2.0f : (d == c ? 1.0f : 0.0f);
            v.h[j] = (_Float16)(sc * cv[j] * wc * wv[j]);
        }
    } else {                               // W panels for the Ssum GEMM
        const int k0 = (p - NPAIR) * 32 + q * 8;
        const float4 w0 = *(const float4*)(w + gl * C_TYPES + k0);
        const float4 w1 = *(const float4*)(w + gl * C_TYPES + k0 + 4);
        const float wv[8] = {w0.x,w0.y,w0.z,w0.w,w1.x,w1.y,w1.z,w1.w};
#pragma unroll
        for (int j = 0; j < 8; ++j) v.h[j] = (_Float16)wv[j];
    }
    *(uint4*)(cwA + (p << 9) + lane * 8) = v.u;
}

// ---- Kernel M: main ----
__global__ __launch_bounds__(1024, 4)
void lognorm_main(const float* __restrict__ Z_mu,
                  const float* __restrict__ Z_sigma,
                  const unsigned short* __restrict__ cwA,
                  float* __restrict__ out)
{
    __shared__ f16x2   x2pT[64][33];     // [gene][d-pair]
    __shared__ f16x2   x1pT[64][33];
    __shared__ _Float16 x2g[64][72];     // [c][gene] f16 scalars (bcast reads)
    __shared__ float   accs[16][S_STATES][66];
    __shared__ float   ssum_s[S_STATES][66];

    const int gt    = blockIdx.x;        // 0..312
    const int tid   = threadIdx.x;       // 0..1023
    const int w     = tid >> 6;          // wave 0..15 = K-interleave slot
    const int lane  = tid & 63;
    const int gl    = lane & 15;
    const int q     = lane >> 4;
    const int gbase = (gt < 312) ? gt * 64 : (G_GENES - 64);   // tail window

    // ---- X-phase: thread -> rows 2dp,2dp+1 ; genes ga,ga+1 (4 exps) ----
    {
        const int dp = tid >> 5;         // 0..31
        const int ga = (tid & 31) * 2;   // 0..62
        const float* zm = Z_mu    + (2*dp) * G_GENES + gbase + ga;
        const float* zs = Z_sigma + (2*dp) * G_GENES + gbase + ga;
        const float2 m0 = *(const float2*)zm;
        const float2 m1 = *(const float2*)(zm + G_GENES);
        const float2 s0 = *(const float2*)zs;
        const float2 s1 = *(const float2*)(zs + G_GENES);
        const float e00 = __expf(fmaf(0.5f*s0.x, s0.x, m0.x)) * 0.25f;
        const float e01 = __expf(fmaf(0.5f*s0.y, s0.y, m0.y)) * 0.25f;
        const float e10 = __expf(fmaf(0.5f*s1.x, s1.x, m1.x)) * 0.25f;
        const float e11 = __expf(fmaf(0.5f*s1.y, s1.y, m1.y)) * 0.25f;
        const float x200 = e00*s0.x, x201 = e01*s0.y;
        const float x210 = e10*s1.x, x211 = e11*s1.y;
        f16x2 a0; a0.x = (_Float16)x200; a0.y = (_Float16)x210;
        f16x2 a1; a1.x = (_Float16)x201; a1.y = (_Float16)x211;
        f16x2 b0; b0.x = (_Float16)e00;  b0.y = (_Float16)e10;
        f16x2 b1; b1.x = (_Float16)e01;  b1.y = (_Float16)e11;
        x2pT[ga][dp]   = a0;  x2pT[ga+1][dp] = a1;
        x1pT[ga][dp]   = b0;  x1pT[ga+1][dp] = b1;
        x2g[2*dp][ga]     = (_Float16)x200;  x2g[2*dp][ga+1]   = (_Float16)x201;
        x2g[2*dp+1][ga]   = (_Float16)x210;  x2g[2*dp+1][ga+1] = (_Float16)x211;
    }
    __syncthreads();

    // ---- xh[dh][jp][t] = x2 d-pairs for the 4 gene-subtiles ----
    f16x2 xh[2][4][4];
#pragma unroll
    for (int dh = 0; dh < 2; ++dh)
#pragma unroll
        for (int t = 0; t < 4; ++t)
#pragma unroll
            for (int jp = 0; jp < 4; ++jp)
                xh[dh][jp][t] = x2pT[gl + 16*t][dh*16 + q*4 + jp];

    // ---- K-loop: 6 iters x {A-load, 4 subtiles x (4 pk_mul + MFMA)} ----
    const unsigned short* Abase = cwA + lane * 8;
    f32x4 acc0 = {0.f,0.f,0.f,0.f}, acc1 = {0.f,0.f,0.f,0.f};
    f32x4 acc2 = {0.f,0.f,0.f,0.f}, acc3 = {0.f,0.f,0.f,0.f};
#pragma unroll
    for (int i = 0; i < 6; ++i) {
        const int p  = i * 16 + w;
        const int dh = (i >= 4) ? 1 : 0;
        const int c  = p - dh * 32;
        Frag8 af; af.u = *(const uint4*)(Abase + (p << 9));
#pragma unroll
        for (int t = 0; t < 4; ++t) {
            const _Float16 xc = x2g[c][gl + 16*t];   // bcast, conflict-free
            f16x2 s; s.x = xc; s.y = xc;
            Frag8 b;
#pragma unroll
            for (int jp = 0; jp < 4; ++jp) b.p[jp] = s * xh[dh][jp][t];
            if      (t == 0) acc0 = __builtin_amdgcn_mfma_f32_16x16x32_f16(af.v, b.v, acc0, 0, 0, 0);
            else if (t == 1) acc1 = __builtin_amdgcn_mfma_f32_16x16x32_f16(af.v, b.v, acc1, 0, 0, 0);
            else if (t == 2) acc2 = __builtin_amdgcn_mfma_f32_16x16x32_f16(af.v, b.v, acc2, 0, 0, 0);
            else             acc3 = __builtin_amdgcn_mfma_f32_16x16x32_f16(af.v, b.v, acc3, 0, 0, 0);
        }
    }
#pragma unroll
    for (int r = 0; r < 4; ++r) {
        accs[w][q*4 + r][gl]      = acc0[r];
        accs[w][q*4 + r][gl + 16] = acc1[r];
        accs[w][q*4 + r][gl + 32] = acc2[r];
        accs[w][q*4 + r][gl + 48] = acc3[r];
    }

    // ---- Ssum GEMM: waves 0..3 -> gene subtile w ----
    if (w < 4) {
        Frag8 wf0, wf1;
        wf0.u = *(const uint4*)(cwA + ((NPAIR + 0) << 9) + lane * 8);
        wf1.u = *(const uint4*)(cwA + ((NPAIR + 1) << 9) + lane * 8);
        Frag8 x1f0, x1f1;
#pragma unroll
        for (int jp = 0; jp < 4; ++jp) {
            x1f0.p[jp] = x1pT[gl + 16*w][q*4 + jp];
            x1f1.p[jp] = x1pT[gl + 16*w][16 + q*4 + jp];
        }
        f32x4 sa = {0.f,0.f,0.f,0.f};
        sa = __builtin_amdgcn_mfma_f32_16x16x32_f16(wf0.v, x1f0.v, sa, 0, 0, 0);
        sa = __builtin_amdgcn_mfma_f32_16x16x32_f16(wf1.v, x1f1.v, sa, 0, 0, 0);
#pragma unroll
        for (int r = 0; r < 4; ++r) ssum_s[q*4 + r][gl + 16*w] = sa[r];
    }
    __syncthreads();

    // ---- epilogue: thread -> (s = tid>>6, gene gx = tid&63) ----
    const int s  = tid >> 6;
    const int gx = tid & 63;
    float vn = 0.f;
#pragma unroll
    for (int k = 0; k < 16; ++k) vn += accs[k][s][gx];
    const float ss   = ssum_s[s][gx];                 // = Ssum/4
    const float rvar = fmaxf(vn, 0.f) / (ss * ss);    // scale cancels
    out[s * G_GENES + gbase + gx] =
        __logf(ss) + 1.3862943611f - 0.5f * rvar;     // + log 4
    out[OUT_HALF + s * G_GENES + gbase + gx] = sqrtf(rvar);
}

extern "C" void kernel_launch(void* const* d_in, const int* in_sizes, int n_in,
                              void* d_out, int out_size, void* d_ws, size_t ws_size,
                              hipStream_t stream) {
    const float* Z_mu      = (const float*)d_in[0];
    const float* Z_sigma   = (const float*)d_in[1];
    const float* corr      = (const float*)d_in[2];
    const float* cell_prob = (const float*)d_in[3];
    float* out = (float*)d_out;
    unsigned short* cwA = (unsigned short*)d_ws;   // 98 KB frag-ordered f16 A

    build_A<<<dim3(NPAIR + 2), dim3(64), 0, stream>>>(corr, cell_prob, cwA);

    const int gtiles = (G_GENES + 63) / 64;        // 313 (last block windows)
    lognorm_main<<<dim3(gtiles), dim3(1024), 0, stream>>>(
        Z_mu, Z_sigma, cwA, out);
}

// Round 14
// 15.603 us; speedup vs baseline: 6.5335x; 1.1491x over previous
//
#include <hip/hip_runtime.h>

// LogNorm moment-matching, v14: v11 with 8-wave K-split (32 genes/block).
// R12 counters: MfmaUtil 4%, VALUBusy 8%, Occ 22% — machine idle, grid-
// limited (625 blocks = 2.44/CU x 4 waves ~ 10 waves/CU). v14 keeps v11's
// A-traffic & tile (32 genes) but splits K over 8 waves: 12 panels/wave
// (half the serial L2 chain), 5000 waves (4.9/SIMD), LDS 33 KB (4 blk/CU).
//
//   e = exp(Z_mu + sigma^2/2); x1' = e/4; x2' = e*sigma/4        (C x G)
//   var_num'[s,g] = sum_{d<=c} sc * (w_sc w_sd corr_cd) * (x2'_c x2'_d)
//   Ssum'[s,g]    = W @ x1'; var = vn'/ss'^2 (scales cancel);
//   mu = log(ss') + log4 - var/2 ; sigma = sqrt(var)
//
// Panels: wave w takes p = i*8 + w, i in [0,12); dh = (i>=8) compile-time.
// MFMA 16x16x32_f16, layout as verified v2-v13:
//   A-frag: lane(q,gl) = A[m=gl][k=q*8+j]   (m = state)
//   B-frag: lane(q,gl) = B[k=q*8+j][n=gl]   (n = gene)
//   C/D:    lane(q,gl) reg r = D[row=q*4+r][col=gl]

#define S_STATES 16
#define C_TYPES  64
#define G_GENES  20000
#define OUT_HALF (S_STATES * G_GENES)
#define NPAIR    96
#define PER_WAVE 12

typedef _Float16 f16x2 __attribute__((ext_vector_type(2)));
typedef _Float16 f16x8 __attribute__((ext_vector_type(8)));
typedef float    f32x4 __attribute__((ext_vector_type(4)));

union Frag8 { f16x2 p[4]; f16x8 v; uint4 u; _Float16 h[8]; };

// ---- Kernel P: frag-ordered f16 A panels (1 KB each; 98 KB total) ----
__global__ __launch_bounds__(64)
void build_A(const float* __restrict__ corr, const float* __restrict__ w,
             unsigned short* __restrict__ cwA)
{
    const int p    = blockIdx.x;          // 0..97
    const int lane = threadIdx.x;
    const int gl   = lane & 15;           // state (A row)
    const int q    = lane >> 4;
    Frag8 v;
    if (p < NPAIR) {
        const int dh = (p >= 64);
        const int c  = dh ? p - 32 : p;
        const int d0 = dh * 32 + q * 8;
        const float wc = w[gl * C_TYPES + c];
        const float4 c0 = *(const float4*)(corr + c * C_TYPES + d0);
        const float4 c1 = *(const float4*)(corr + c * C_TYPES + d0 + 4);
        const float4 w0 = *(const float4*)(w + gl * C_TYPES + d0);
        const float4 w1 = *(const float4*)(w + gl * C_TYPES + d0 + 4);
        const float cv[8] = {c0.x,c0.y,c0.z,c0.w,c1.x,c1.y,c1.z,c1.w};
        const float wv[8] = {w0.x,w0.y,w0.z,w0.w,w1.x,w1.y,w1.z,w1.w};
#pragma unroll
        for (int j = 0; j < 8; ++j) {
            const int d = d0 + j;
            const float sc = (d < c) ? 2.0f : (d == c ? 1.0f : 0.0f);
            v.h[j] = (_Float16)(sc * cv[j] * wc * wv[j]);
        }
    } else {                               // W panels for the Ssum GEMM
        const int k0 = (p - NPAIR) * 32 + q * 8;
        const float4 w0 = *(const float4*)(w + gl * C_TYPES + k0);
        const float4 w1 = *(const float4*)(w + gl * C_TYPES + k0 + 4);
        const float wv[8] = {w0.x,w0.y,w0.z,w0.w,w1.x,w1.y,w1.z,w1.w};
#pragma unroll
        for (int j = 0; j < 8; ++j) v.h[j] = (_Float16)wv[j];
    }
    *(uint4*)(cwA + (p << 9) + lane * 8) = v.u;
}

// ---- Kernel M: main (512 thr = 8 waves, 32 genes/block) ----
__global__ __launch_bounds__(512, 6)
void lognorm_main(const float* __restrict__ Z_mu,
                  const float* __restrict__ Z_sigma,
                  const unsigned short* __restrict__ cwA,
                  float* __restrict__ out)
{
    __shared__ f16x2 x2pT[32][35];       // [gene][d-pair]
    __shared__ f16x2 x1pT[32][35];
    __shared__ f16x2 x2tp[C_TYPES][21];  // [c][(g,g+16) pair]; broadcast
    __shared__ float accs[8][S_STATES][33];
    __shared__ float ssum_s[S_STATES][33];

    const int gt    = blockIdx.x;        // 0..624, 32 genes (exact)
    const int tid   = threadIdx.x;       // 0..511
    const int w     = tid >> 6;          // wave 0..7 = K-interleave slot
    const int lane  = tid & 63;
    const int gl    = lane & 15;
    const int q     = lane >> 4;
    const int gbase = gt * 32;

    // ---- X-phase: thread -> rows 2dp,2dp+1 ; genes gq, gq+16 (4 exps) ----
    {
        const int dp = tid >> 4;         // 0..31
        const int gq = tid & 15;         // 0..15
        const float* zm = Z_mu    + (2*dp) * G_GENES + gbase + gq;
        const float* zs = Z_sigma + (2*dp) * G_GENES + gbase + gq;
        const float m00 = zm[0], m01 = zm[16];
        const float m10 = zm[G_GENES], m11 = zm[G_GENES + 16];
        const float s00 = zs[0], s01 = zs[16];
        const float s10 = zs[G_GENES], s11 = zs[G_GENES + 16];
        const float e00 = __expf(fmaf(0.5f*s00, s00, m00)) * 0.25f;
        const float e01 = __expf(fmaf(0.5f*s01, s01, m01)) * 0.25f;
        const float e10 = __expf(fmaf(0.5f*s10, s10, m10)) * 0.25f;
        const float e11 = __expf(fmaf(0.5f*s11, s11, m11)) * 0.25f;
        const float x200 = e00*s00, x201 = e01*s01;   // row 2dp,   gq / gq+16
        const float x210 = e10*s10, x211 = e11*s11;   // row 2dp+1, gq / gq+16
        f16x2 a;
        a.x = (_Float16)x200; a.y = (_Float16)x210; x2pT[gq][dp]      = a;
        a.x = (_Float16)x201; a.y = (_Float16)x211; x2pT[gq + 16][dp] = a;
        a.x = (_Float16)e00;  a.y = (_Float16)e10;  x1pT[gq][dp]      = a;
        a.x = (_Float16)e01;  a.y = (_Float16)e11;  x1pT[gq + 16][dp] = a;
        a.x = (_Float16)x200; a.y = (_Float16)x201; x2tp[2*dp][gq]    = a;
        a.x = (_Float16)x210; a.y = (_Float16)x211; x2tp[2*dp+1][gq]  = a;
    }
    __syncthreads();

    // ---- B sources: xh (16 reads, reused 6x), xct (12 broadcast) ----
    f16x2 xh[2][4][2];                   // [dh][jp][t]
#pragma unroll
    for (int dh = 0; dh < 2; ++dh)
#pragma unroll
        for (int t = 0; t < 2; ++t)
#pragma unroll
            for (int jp = 0; jp < 4; ++jp)
                xh[dh][jp][t] = x2pT[gl + 16*t][dh*16 + q*4 + jp];

    f16x2 xct[PER_WAVE];
#pragma unroll
    for (int i = 0; i < PER_WAVE; ++i) {
        const int c = i*8 + w - ((i >= 8) ? 32 : 0);
        xct[i] = x2tp[c][gl];
    }

    // ---- K-loop: 12 x {A-load(b128), 8 pk_mul, 2 MFMA}; 4 acc chains ----
    const unsigned short* Abase = cwA + (w << 9) + lane * 8;
    f32x4 acc0a = {0.f,0.f,0.f,0.f}, acc0b = {0.f,0.f,0.f,0.f};
    f32x4 acc1a = {0.f,0.f,0.f,0.f}, acc1b = {0.f,0.f,0.f,0.f};
#pragma unroll
    for (int i = 0; i < PER_WAVE; ++i) {
        Frag8 af; af.u = *(const uint4*)(Abase + (i << 12));
        const int dh = (i >= 8) ? 1 : 0;
        Frag8 b0, b1;
#pragma unroll
        for (int jp = 0; jp < 4; ++jp) {
            f16x2 s0; s0.x = xct[i].x; s0.y = xct[i].x;
            f16x2 s1; s1.x = xct[i].y; s1.y = xct[i].y;
            b0.p[jp] = s0 * xh[dh][jp][0];
            b1.p[jp] = s1 * xh[dh][jp][1];
        }
        if (i & 1) {
            acc0b = __builtin_amdgcn_mfma_f32_16x16x32_f16(af.v, b0.v, acc0b, 0, 0, 0);
            acc1b = __builtin_amdgcn_mfma_f32_16x16x32_f16(af.v, b1.v, acc1b, 0, 0, 0);
        } else {
            acc0a = __builtin_amdgcn_mfma_f32_16x16x32_f16(af.v, b0.v, acc0a, 0, 0, 0);
            acc1a = __builtin_amdgcn_mfma_f32_16x16x32_f16(af.v, b1.v, acc1a, 0, 0, 0);
        }
    }
    const f32x4 acc0 = acc0a + acc0b;
    const f32x4 acc1 = acc1a + acc1b;
#pragma unroll
    for (int r = 0; r < 4; ++r) {
        accs[w][q*4 + r][gl]      = acc0[r];
        accs[w][q*4 + r][gl + 16] = acc1[r];
    }

    // ---- Ssum GEMM: waves 0,1 -> gene subtiles 0,1 ----
    if (w < 2) {
        Frag8 wf0, wf1;
        wf0.u = *(const uint4*)(cwA + ((NPAIR + 0) << 9) + lane * 8);
        wf1.u = *(const uint4*)(cwA + ((NPAIR + 1) << 9) + lane * 8);
        Frag8 x1f[2];
#pragma unroll
        for (int kk = 0; kk < 2; ++kk)
#pragma unroll
            for (int jp = 0; jp < 4; ++jp)
                x1f[kk].p[jp] = x1pT[gl + 16*w][kk*16 + q*4 + jp];
        f32x4 sa = {0.f,0.f,0.f,0.f};
        sa = __builtin_amdgcn_mfma_f32_16x16x32_f16(wf0.v, x1f[0].v, sa, 0, 0, 0);
        sa = __builtin_amdgcn_mfma_f32_16x16x32_f16(wf1.v, x1f[1].v, sa, 0, 0, 0);
#pragma unroll
        for (int r = 0; r < 4; ++r) ssum_s[q*4 + r][gl + 16*w] = sa[r];
    }
    __syncthreads();

    // ---- epilogue: thread -> (s = tid>>5, gene gx = tid&31) ----
    const int s  = tid >> 5;
    const int gx = tid & 31;
    float vn = 0.f;
#pragma unroll
    for (int k = 0; k < 8; ++k) vn += accs[k][s][gx];
    const float ss   = ssum_s[s][gx];                 // = Ssum/4
    const float rvar = fmaxf(vn, 0.f) / (ss * ss);    // scale cancels
    out[s * G_GENES + gbase + gx] =
        __logf(ss) + 1.3862943611f - 0.5f * rvar;     // + log 4
    out[OUT_HALF + s * G_GENES + gbase + gx] = sqrtf(rvar);
}

extern "C" void kernel_launch(void* const* d_in, const int* in_sizes, int n_in,
                              void* d_out, int out_size, void* d_ws, size_t ws_size,
                              hipStream_t stream) {
    const float* Z_mu      = (const float*)d_in[0];
    const float* Z_sigma   = (const float*)d_in[1];
    const float* corr      = (const float*)d_in[2];
    const float* cell_prob = (const float*)d_in[3];
    float* out = (float*)d_out;
    unsigned short* cwA = (unsigned short*)d_ws;   // 98 KB frag-ordered f16 A

    build_A<<<dim3(NPAIR + 2), dim3(64), 0, stream>>>(corr, cell_prob, cwA);

    const int gtiles = G_GENES / 32;               // 625, exact
    lognorm_main<<<dim3(gtiles), dim3(512), 0, stream>>>(
        Z_mu, Z_sigma, cwA, out);
}